// Round 1
// baseline (417.645 us; speedup 1.0000x reference)
//
#include <hip/hip_runtime.h>
#include <math.h>

#define CAP   2048    // max edges out of Co / max |S|
#define MCAP  32768   // max edges whose from-node is in S

// ---------------- device math helpers (double precision) ----------------

__device__ __forceinline__ double dfact(int n){
  double r = 1.0;
  for (int i = 2; i <= n; ++i) r *= (double)i;
  return r;
}

__device__ double cg_coef(int j1,int m1,int j2,int m2,int j3,int m3){
  if (m1 + m2 != m3) return 0.0;
  double pref = sqrt((2.0*j3+1.0) * dfact(j1+j2-j3) * dfact(j1-j2+j3) * dfact(-j1+j2+j3)
                     / dfact(j1+j2+j3+1));
  pref *= sqrt(dfact(j1+m1)*dfact(j1-m1)*dfact(j2+m2)*dfact(j2-m2)*dfact(j3+m3)*dfact(j3-m3));
  double s = 0.0;
  for (int k = 0; k <= j1+j2-j3; ++k){
    int d2 = j1-m1-k, d3 = j2+m2-k, d4 = j3-j2+m1+k, d5 = j3-j1-m2+k;
    if (d2 < 0 || d3 < 0 || d4 < 0 || d5 < 0) continue;
    double den = dfact(k)*dfact(j1+j2-j3-k)*dfact(d2)*dfact(d3)*dfact(d4)*dfact(d5);
    s += ((k & 1) ? -1.0 : 1.0) / den;
  }
  return pref * s;
}

__device__ double wigner_c_val(int j1,int j2,int j3,int m1,int m2,int m3){
  if (m1+m2+m3 != 0) return 0.0;
  int e = j1 - j2 - m3;
  double sign = (e & 1) ? -1.0 : 1.0;   // (-1)^e, parity correct for negative e
  return sign / sqrt(2.0*j3+1.0) * cg_coef(j1,m1,j2,m2,j3,-m3);
}

// rows of conj(U_real(l)) — at most 2 nonzeros per row
__device__ int conjU_row(int l, int i, int* cols, double* re, double* im){
  int mr = i - l;
  const double irt2 = 0.70710678118654752440;
  if (mr == 0){ cols[0]=l; re[0]=1.0; im[0]=0.0; return 1; }
  int m = mr > 0 ? mr : -mr;
  double sgn = (m & 1) ? -1.0 : 1.0;   // (-1)^m
  if (mr > 0){
    cols[0]=l+m; re[0]=sgn*irt2; im[0]=0.0;
    cols[1]=l-m; re[1]=irt2;     im[1]=0.0;
  } else {
    cols[0]=l+m; re[0]=0.0; im[0]= sgn*irt2;   // conj(-i*(-1)^m/rt2)
    cols[1]=l-m; re[1]=0.0; im[1]=-irt2;       // conj(i/rt2)
  }
  return 2;
}

// Wr[i,j,k] of real Wigner 3j for (j1,j2,j3)
__device__ double wr_entry(int j1,int j2,int j3,int i,int j,int k){
  int c1[2], c2[2], c3[2];
  double r1[2], i1[2], r2[2], i2[2], r3[2], i3[2];
  int n1 = conjU_row(j1,i,c1,r1,i1);
  int n2 = conjU_row(j2,j,c2,r2,i2);
  int n3 = conjU_row(j3,k,c3,r3,i3);
  double acc = 0.0;
  for (int a=0;a<n1;a++)
    for (int b=0;b<n2;b++)
      for (int c=0;c<n3;c++){
        int m1 = c1[a]-j1, m2 = c2[b]-j2, m3 = c3[c]-j3;
        if (m1+m2+m3 != 0) continue;
        double wc = wigner_c_val(j1,j2,j3,m1,m2,m3);
        double pr = r1[a]*r2[b] - i1[a]*i2[b];
        double pi = r1[a]*i2[b] + i1[a]*r2[b];
        double qr = pr*r3[c] - pi*i3[c];
        acc += wc*qr;
      }
  return acc;
}

// real spherical harmonics l=0..5 (36 comps), matches reference recurrences
__device__ void compute_sh36(double ex, double ey, double ez, double* sh){
  double r = sqrt(ex*ex+ey*ey+ez*ez);
  double x = ex/r, y = ey/r, z = ez/r;
  double phi = atan2(y, x);
  double t = 1.0 - z*z;
  t = t < 0.0 ? 0.0 : (t > 1.0 ? 1.0 : t);
  double s = sqrt(t);
  double P[6][6];
  P[0][0] = 1.0;
  for (int m=1;m<=5;m++) P[m][m] = (double)(2*m-1)*s*P[m-1][m-1];
  for (int m=0;m<5;m++)  P[m+1][m] = (double)(2*m+1)*z*P[m][m];
  for (int l=2;l<=5;l++)
    for (int m=0;m<=l-2;m++)
      P[l][m] = ((double)(2*l-1)*z*P[l-1][m] - (double)(l-1+m)*P[l-2][m])/(double)(l-m);
  for (int l=0;l<=5;l++){
    for (int m=-l;m<=l;m++){
      int am = m < 0 ? -m : m;
      double c = sqrt((double)(2*l+1)*dfact(l-am)/dfact(l+am));
      if (m != 0) c *= 1.41421356237309504880;
      double ang = (m < 0) ? sin((double)am*phi) : ((m > 0) ? cos((double)am*phi) : 1.0);
      sh[l*l + m + l] = c * P[l][am] * ang;
    }
  }
}

// ---------------- kernels ----------------

// K1: compute Wigner tables into ws (graph-safe, no host memcpy)
__global__ void w3j_setup_kernel(double* __restrict__ w3j1, double* __restrict__ w3j2){
  int tid = threadIdx.x, nt = blockDim.x;
  const int l1off[5] = {0,1,10,35,84};
  for (int l=0;l<5;l++){
    int n = 2*l+1;
    for (int t=tid; t<n*n; t+=nt){
      int j = t/n, k = t%n;
      w3j1[l1off[l]+t] = wr_entry(0,l,l, 0,j,k);
    }
  }
  const int pl1[11]  = {0,1,1,2,2,2,3,3,3,4,4};
  const int pl2[11]  = {2,1,3,0,2,4,1,3,5,2,4};
  const int poff[11] = {0,25,70,175,200,325,550,655,900,1285,1510};
  for (int p=0;p<11;p++){
    int l1 = pl1[p], l2 = pl2[p];
    int n1 = 2*l1+1, n2 = 2*l2+1, tot = n1*n2*5;
    for (int t=tid; t<tot; t+=nt){
      int i = t/(n2*5), rem = t%(n2*5), j = rem/5, k = rem%5;
      w3j2[poff[p]+t] = wr_entry(l1,l2,2, i,j,k);
    }
  }
}

// K2: bincount(edge_to)
__global__ void count_kernel(const int* __restrict__ ei, int* __restrict__ counts, int E){
  int e = blockIdx.x*blockDim.x + threadIdx.x;
  if (e < E) atomicAdd(&counts[ei[2*e+1]], 1);
}

// K3: argmax with first-index tie-break via packed key
__global__ void argmax_kernel(const int* __restrict__ counts, unsigned long long* __restrict__ key, int N){
  __shared__ unsigned long long sred[256];
  int i = blockIdx.x*blockDim.x + threadIdx.x;
  unsigned long long k = 0;
  if (i < N){
    unsigned long long c = (unsigned long long)(unsigned int)counts[i];
    k = (c << 32) | (unsigned int)(N-1-i);   // max count, then min index
  }
  sred[threadIdx.x] = k;
  __syncthreads();
  for (int s = 128; s > 0; s >>= 1){
    if (threadIdx.x < s){
      unsigned long long o = sred[threadIdx.x+s];
      if (o > sred[threadIdx.x]) sred[threadIdx.x] = o;
    }
    __syncthreads();
  }
  if (threadIdx.x == 0) atomicMax(key, sred[0]);
}

// K4: collect edges with edge_from==Co; flag their targets (set S) with compact slots
__global__ void find_co_kernel(const int* __restrict__ ei, const unsigned long long* __restrict__ key,
                               int* __restrict__ flag, int* __restrict__ co_count,
                               int* __restrict__ s_count, int* __restrict__ co_edges, int N, int E){
  int e = blockIdx.x*blockDim.x + threadIdx.x;
  if (e >= E) return;
  int Co = N - 1 - (int)(unsigned int)(*key & 0xffffffffull);
  if (ei[2*e] != Co) return;
  int p = atomicAdd(co_count, 1);
  if (p < CAP) co_edges[p] = e;
  int v = ei[2*e+1];
  if (atomicCAS(&flag[v], 0, -1) == 0){
    int slot = atomicAdd(s_count, 1);
    flag[v] = (slot < CAP) ? (slot + 1) : 0;
  }
}

// K5a: collect edges with edge_from in S
__global__ void collect_kernel(const int* __restrict__ ei, const int* __restrict__ flag,
                               int* __restrict__ m_count, int* __restrict__ m_edges, int E){
  int e = blockIdx.x*blockDim.x + threadIdx.x;
  if (e >= E) return;
  if (flag[ei[2*e]] > 0){
    int p = atomicAdd(m_count, 1);
    if (p < MCAP) m_edges[p] = e;
  }
}

// K5b: full per-edge pipeline (emb -> MLP -> tp1) for S-edges; accumulate node features
__global__ void feat_kernel(const int* __restrict__ ei, const int* __restrict__ flag,
                            const float* __restrict__ pos, const float* __restrict__ x,
                            const float* __restrict__ w1, const float* __restrict__ w2,
                            const double* __restrict__ w3j1,
                            const int* __restrict__ m_count, const int* __restrict__ m_edges,
                            double* __restrict__ node_acc){
  int idx = blockIdx.x*blockDim.x + threadIdx.x;
  int n = *m_count; if (n > MCAP) n = MCAP;
  if (idx >= n) return;
  int e = m_edges[idx];
  int f = ei[2*e], t = ei[2*e+1];
  int slot = flag[f] - 1;
  if (slot < 0 || slot >= CAP) return;

  double ex = (double)pos[3*t+0] - (double)pos[3*f+0];
  double ey = (double)pos[3*t+1] - (double)pos[3*f+1];
  double ez = (double)pos[3*t+2] - (double)pos[3*f+2];
  double sh[36];
  compute_sh36(ex,ey,ez,sh);
  double d = sqrt(ex*ex+ey*ey+ez*ez);

  // soft one-hot radial embedding
  double emb[20];
  const double step = 3.0/21.0;
  const double cemb = 1.14136 * exp(2.0);
  for (int jb=0;jb<20;jb++){
    double v = step*(double)(jb+1);
    double diff = (d - v)/step;
    double a = diff + 1.0, b = 1.0 - diff;
    double sa = (a > 0.0) ? exp(-1.0/a) : 0.0;
    double sb = (b > 0.0) ? exp(-1.0/b) : 0.0;
    emb[jb] = cemb * sa * sb;
  }
  // MLP: h = silu(emb@W1/sqrt(20))*1.679 ; tw = h@W2/sqrt(50)
  double tw[5] = {0,0,0,0,0};
  const double is20 = 0.22360679774997896964;
  const double is50 = 0.14142135623730950488;
  for (int kk=0;kk<50;kk++){
    double z = 0.0;
    for (int jb=0;jb<20;jb++) z += emb[jb]*(double)w1[jb*50+kk];
    z *= is20;
    double hk = (z / (1.0 + exp(-z))) * 1.679;
    for (int i=0;i<5;i++) tw[i] += hk * (double)w2[kk*5+i];
  }
  for (int i=0;i<5;i++) tw[i] *= is50;

  double xs = (double)x[t];
  // tp1: per l, alpha*(w)*(x)*(sh_l @ W3J1_l)
  const int w1off[5] = {0,1,10,35,84};
  int fo = 0;
  for (int l=0;l<5;l++){
    int nl = 2*l+1;
    double scale = sqrt((double)nl) * tw[l] * xs;
    for (int kq=0;kq<nl;kq++){
      double acc = 0.0;
      for (int jq=0;jq<nl;jq++) acc += sh[l*l+jq]*w3j1[w1off[l]+jq*nl+kq];
      atomicAdd(&node_acc[slot*25 + fo + kq], scale*acc);
    }
    fo += nl;
  }
}

// K6: tp2 on Co-edges + reduce to the 5-component output
__global__ void out_kernel(const int* __restrict__ ei, const int* __restrict__ flag,
                           const float* __restrict__ pos, const double* __restrict__ node_acc,
                           const double* __restrict__ w3j2, const float* __restrict__ tp2w,
                           const int* __restrict__ co_count, const int* __restrict__ co_edges,
                           float* __restrict__ out){
  __shared__ double red[64*5];
  double acc[5] = {0,0,0,0,0};
  int n = *co_count; if (n > CAP) n = CAP;
  const double inv_sqrt6 = 0.40824829046386301637;   // 1/sqrt(NUM_NEIGHBORS)
  const double alpha2    = 0.67419986246324704794;   // sqrt(5/11)
  const int pl1[11]  = {0,1,1,2,2,2,3,3,3,4,4};
  const int pl2[11]  = {2,1,3,0,2,4,1,3,5,2,4};
  const int poff[11] = {0,25,70,175,200,325,550,655,900,1285,1510};

  for (int idx = threadIdx.x; idx < n; idx += blockDim.x){
    int e = co_edges[idx];
    int f = ei[2*e], t = ei[2*e+1];
    int slot = flag[t] - 1;
    if (slot < 0 || slot >= CAP) continue;
    double ex = (double)pos[3*t+0] - (double)pos[3*f+0];
    double ey = (double)pos[3*t+1] - (double)pos[3*f+1];
    double ez = (double)pos[3*t+2] - (double)pos[3*f+2];
    double sh[36];
    compute_sh36(ex,ey,ez,sh);
    double nodev[25];
    for (int j=0;j<25;j++) nodev[j] = node_acc[slot*25+j]*inv_sqrt6;
    for (int p=0;p<11;p++){
      int l1 = pl1[p], l2 = pl2[p], n1 = 2*l1+1, n2 = 2*l2+1;
      const double* W = w3j2 + poff[p];
      double wp = alpha2*(double)tp2w[p];
      for (int i=0;i<n1;i++){
        double fi = nodev[l1*l1+i];
        for (int j=0;j<n2;j++){
          double fs = wp*fi*sh[l2*l2+j];
          const double* Wij = W + (i*n2+j)*5;
          for (int k=0;k<5;k++) acc[k] += fs*Wij[k];
        }
      }
    }
  }
  for (int k=0;k<5;k++) red[threadIdx.x*5+k] = acc[k];
  __syncthreads();
  if (threadIdx.x < 5){
    double s = 0.0;
    for (int t2=0;t2<64;t2++) s += red[t2*5+threadIdx.x];
    out[threadIdx.x] = (float)s;
  }
}

// ---------------- launcher ----------------

extern "C" void kernel_launch(void* const* d_in, const int* in_sizes, int n_in,
                              void* d_out, int out_size, void* d_ws, size_t ws_size,
                              hipStream_t stream){
  const float* x    = (const float*)d_in[0];
  const float* pos  = (const float*)d_in[1];
  const int*   ei   = (const int*)d_in[2];
  const float* w1   = (const float*)d_in[3];
  const float* w2   = (const float*)d_in[4];
  const float* tp2w = (const float*)d_in[5];
  int N = in_sizes[0];
  int E = in_sizes[2] / 2;

  char* ws = (char*)d_ws;
  size_t o = 0;
  int* counts = (int*)(ws + o); o += (size_t)N*4;
  int* flag   = (int*)(ws + o); o += (size_t)N*4;
  o = (o + 7) & ~(size_t)7;
  unsigned long long* key = (unsigned long long*)(ws + o); o += 8;
  int* co_count = (int*)(ws + o); o += 4;
  int* s_count  = (int*)(ws + o); o += 4;
  int* m_count  = (int*)(ws + o); o += 8;            // 4 bytes + pad
  int* co_edges = (int*)(ws + o); o += (size_t)CAP*4;
  int* m_edges  = (int*)(ws + o); o += (size_t)MCAP*4;
  o = (o + 7) & ~(size_t)7;
  double* node_acc = (double*)(ws + o); o += (size_t)CAP*25*8;
  size_t zero_bytes = o;
  double* w3j1 = (double*)(ws + o); o += 165*8;
  double* w3j2 = (double*)(ws + o); o += 1915*8;

  hipMemsetAsync(d_ws, 0, zero_bytes, stream);

  w3j_setup_kernel<<<1, 256, 0, stream>>>(w3j1, w3j2);

  int eblocks = (E + 255)/256;
  int nblocks = (N + 255)/256;
  count_kernel  <<<eblocks, 256, 0, stream>>>(ei, counts, E);
  argmax_kernel <<<nblocks, 256, 0, stream>>>(counts, key, N);
  find_co_kernel<<<eblocks, 256, 0, stream>>>(ei, key, flag, co_count, s_count, co_edges, N, E);
  collect_kernel<<<eblocks, 256, 0, stream>>>(ei, flag, m_count, m_edges, E);
  feat_kernel   <<<(MCAP+255)/256, 256, 0, stream>>>(ei, flag, pos, x, w1, w2, w3j1,
                                                     m_count, m_edges, node_acc);
  out_kernel    <<<1, 64, 0, stream>>>(ei, flag, pos, node_acc, w3j2, tp2w,
                                       co_count, co_edges, (float*)d_out);
}

// Round 2
// 280.410 us; speedup vs baseline: 1.4894x; 1.4894x over previous
//
#include <hip/hip_runtime.h>
#include <math.h>

#define CAP   2048    // max edges out of Co / max |S|
#define MCAP  32768   // max edges whose from-node is in S

// ---------------- device math helpers (double precision) ----------------

__device__ double cg_coef_lut(int j1,int m1,int j2,int m2,int j3,int m3, const double* __restrict__ fact){
  if (m1 + m2 != m3) return 0.0;
  double pref = sqrt((2.0*j3+1.0) * fact[j1+j2-j3] * fact[j1-j2+j3] * fact[-j1+j2+j3]
                     / fact[j1+j2+j3+1]);
  pref *= sqrt(fact[j1+m1]*fact[j1-m1]*fact[j2+m2]*fact[j2-m2]*fact[j3+m3]*fact[j3-m3]);
  double s = 0.0;
  for (int k = 0; k <= j1+j2-j3; ++k){
    int d2 = j1-m1-k, d3 = j2+m2-k, d4 = j3-j2+m1+k, d5 = j3-j1-m2+k;
    if (d2 < 0 || d3 < 0 || d4 < 0 || d5 < 0) continue;
    double den = fact[k]*fact[j1+j2-j3-k]*fact[d2]*fact[d3]*fact[d4]*fact[d5];
    s += ((k & 1) ? -1.0 : 1.0) / den;
  }
  return pref * s;
}

__device__ double wigner_c_val_lut(int j1,int j2,int j3,int m1,int m2,int m3, const double* __restrict__ fact){
  if (m1+m2+m3 != 0) return 0.0;
  int e = j1 - j2 - m3;
  double sign = (e & 1) ? -1.0 : 1.0;   // (-1)^e, parity correct for negative e
  return sign / sqrt(2.0*j3+1.0) * cg_coef_lut(j1,m1,j2,m2,j3,-m3,fact);
}

// rows of conj(U_real(l)) — at most 2 nonzeros per row
__device__ int conjU_row(int l, int i, int* cols, double* re, double* im){
  int mr = i - l;
  const double irt2 = 0.70710678118654752440;
  if (mr == 0){ cols[0]=l; re[0]=1.0; im[0]=0.0; return 1; }
  int m = mr > 0 ? mr : -mr;
  double sgn = (m & 1) ? -1.0 : 1.0;   // (-1)^m
  if (mr > 0){
    cols[0]=l+m; re[0]=sgn*irt2; im[0]=0.0;
    cols[1]=l-m; re[1]=irt2;     im[1]=0.0;
  } else {
    cols[0]=l+m; re[0]=0.0; im[0]= sgn*irt2;   // conj(-i*(-1)^m/rt2)
    cols[1]=l-m; re[1]=0.0; im[1]=-irt2;       // conj(i/rt2)
  }
  return 2;
}

__device__ __forceinline__ double dfact_rt(int n){
  double r = 1.0;
  for (int i = 2; i <= n; ++i) r *= (double)i;
  return r;
}

// real spherical harmonics l=0..5 (36 comps), matches reference recurrences
__device__ void compute_sh36(double ex, double ey, double ez, double* sh){
  double r = sqrt(ex*ex+ey*ey+ez*ez);
  double x = ex/r, y = ey/r, z = ez/r;
  double phi = atan2(y, x);
  double t = 1.0 - z*z;
  t = t < 0.0 ? 0.0 : (t > 1.0 ? 1.0 : t);
  double s = sqrt(t);
  double P[6][6];
  P[0][0] = 1.0;
  for (int m=1;m<=5;m++) P[m][m] = (double)(2*m-1)*s*P[m-1][m-1];
  for (int m=0;m<5;m++)  P[m+1][m] = (double)(2*m+1)*z*P[m][m];
  for (int l=2;l<=5;l++)
    for (int m=0;m<=l-2;m++)
      P[l][m] = ((double)(2*l-1)*z*P[l-1][m] - (double)(l-1+m)*P[l-2][m])/(double)(l-m);
  for (int l=0;l<=5;l++){
    for (int m=-l;m<=l;m++){
      int am = m < 0 ? -m : m;
      double c = sqrt((double)(2*l+1)*dfact_rt(l-am)/dfact_rt(l+am));
      if (m != 0) c *= 1.41421356237309504880;
      double ang = (m < 0) ? sin((double)am*phi) : ((m > 0) ? cos((double)am*phi) : 1.0);
      sh[l*l + m + l] = c * P[l][am] * ang;
    }
  }
}

// ---------------- kernels ----------------

// K1: Wigner tables, one thread per (entry, term). Tables must be pre-zeroed.
// 2080 entries x 8 term-slots = 16640 threads. LDS factorial LUT kills the
// dfact loops that made the serial version 164 us.
__global__ void w3j_setup_kernel(double* __restrict__ w3j1, double* __restrict__ w3j2){
  __shared__ double sfact[16];
  if (threadIdx.x == 0){
    double r = 1.0;
    sfact[0] = 1.0;
    for (int i = 1; i < 16; ++i){ r *= (double)i; sfact[i] = r; }
  }
  __syncthreads();

  int gid = blockIdx.x*blockDim.x + threadIdx.x;
  int entry = gid >> 3;
  int combo = gid & 7;
  if (entry >= 165 + 1915) return;

  int j1, j2, j3, ii, jj, kk;
  double* dst;
  if (entry < 165){
    const int l1off[5] = {0,1,10,35,84};
    int l = 4;
    for (int q = 1; q < 5; ++q) if (entry < l1off[q]){ l = q-1; break; }
    int t = entry - l1off[l];
    int n = 2*l+1;
    j1 = 0; j2 = l; j3 = l;
    ii = 0; jj = t / n; kk = t % n;
    dst = &w3j1[entry];
  } else {
    int t2 = entry - 165;
    const int pl1[11]  = {0,1,1,2,2,2,3,3,3,4,4};
    const int pl2[11]  = {2,1,3,0,2,4,1,3,5,2,4};
    const int poff[11] = {0,25,70,175,200,325,550,655,900,1285,1510};
    int p = 10;
    for (int q = 1; q < 11; ++q) if (t2 < poff[q]){ p = q-1; break; }
    int t = t2 - poff[p];
    j1 = pl1[p]; j2 = pl2[p]; j3 = 2;
    int n2 = 2*j2+1;
    ii = t / (n2*5); int rem = t % (n2*5); jj = rem / 5; kk = rem % 5;
    dst = &w3j2[t2];
  }

  int c1[2], c2[2], c3[2];
  double r1[2], i1[2], r2[2], i2[2], r3[2], i3[2];
  int n1 = conjU_row(j1, ii, c1, r1, i1);
  int n2 = conjU_row(j2, jj, c2, r2, i2);
  int n3 = conjU_row(j3, kk, c3, r3, i3);
  int a = (combo >> 2) & 1, b = (combo >> 1) & 1, c = combo & 1;
  if (a >= n1 || b >= n2 || c >= n3) return;

  int m1 = c1[a]-j1, m2 = c2[b]-j2, m3 = c3[c]-j3;
  if (m1 + m2 + m3 != 0) return;
  double wc = wigner_c_val_lut(j1,j2,j3,m1,m2,m3,sfact);
  if (wc == 0.0) return;
  double pr = r1[a]*r2[b] - i1[a]*i2[b];
  double pi = r1[a]*i2[b] + i1[a]*r2[b];
  double qr = pr*r3[c] - pi*i3[c];
  atomicAdd(dst, wc*qr);
}

// K2: bincount(edge_to)
__global__ void count_kernel(const int2* __restrict__ ei, int* __restrict__ counts, int E){
  int e = blockIdx.x*blockDim.x + threadIdx.x;
  if (e < E) atomicAdd(&counts[ei[e].y], 1);
}

// K3: argmax with first-index tie-break via packed key
__global__ void argmax_kernel(const int* __restrict__ counts, unsigned long long* __restrict__ key, int N){
  __shared__ unsigned long long sred[256];
  int i = blockIdx.x*blockDim.x + threadIdx.x;
  unsigned long long k = 0;
  if (i < N){
    unsigned long long c = (unsigned long long)(unsigned int)counts[i];
    k = (c << 32) | (unsigned int)(N-1-i);   // max count, then min index
  }
  sred[threadIdx.x] = k;
  __syncthreads();
  for (int s = 128; s > 0; s >>= 1){
    if (threadIdx.x < s){
      unsigned long long o = sred[threadIdx.x+s];
      if (o > sred[threadIdx.x]) sred[threadIdx.x] = o;
    }
    __syncthreads();
  }
  if (threadIdx.x == 0) atomicMax(key, sred[0]);
}

// K4: collect edges with edge_from==Co; flag their targets (set S) with compact slots
__global__ void find_co_kernel(const int2* __restrict__ ei, const unsigned long long* __restrict__ key,
                               int* __restrict__ flag, int* __restrict__ co_count,
                               int* __restrict__ s_count, int* __restrict__ co_edges, int N, int E){
  int e = blockIdx.x*blockDim.x + threadIdx.x;
  if (e >= E) return;
  int Co = N - 1 - (int)(unsigned int)(*key & 0xffffffffull);
  int2 fe = ei[e];
  if (fe.x != Co) return;
  int p = atomicAdd(co_count, 1);
  if (p < CAP) co_edges[p] = e;
  int v = fe.y;
  if (atomicCAS(&flag[v], 0, -1) == 0){
    int slot = atomicAdd(s_count, 1);
    flag[v] = (slot < CAP) ? (slot + 1) : 0;
  }
}

// K5a: collect edges with edge_from in S
__global__ void collect_kernel(const int2* __restrict__ ei, const int* __restrict__ flag,
                               int* __restrict__ m_count, int* __restrict__ m_edges, int E){
  int e = blockIdx.x*blockDim.x + threadIdx.x;
  if (e >= E) return;
  if (flag[ei[e].x] > 0){
    int p = atomicAdd(m_count, 1);
    if (p < MCAP) m_edges[p] = e;
  }
}

// K5b: full per-edge pipeline (emb -> MLP -> tp1) for S-edges; accumulate node features
__global__ void feat_kernel(const int2* __restrict__ ei, const int* __restrict__ flag,
                            const float* __restrict__ pos, const float* __restrict__ x,
                            const float* __restrict__ w1, const float* __restrict__ w2,
                            const double* __restrict__ w3j1,
                            const int* __restrict__ m_count, const int* __restrict__ m_edges,
                            double* __restrict__ node_acc){
  int idx = blockIdx.x*blockDim.x + threadIdx.x;
  int n = *m_count; if (n > MCAP) n = MCAP;
  if (idx >= n) return;
  int e = m_edges[idx];
  int2 fe = ei[e];
  int f = fe.x, t = fe.y;
  int slot = flag[f] - 1;
  if (slot < 0 || slot >= CAP) return;

  double ex = (double)pos[3*t+0] - (double)pos[3*f+0];
  double ey = (double)pos[3*t+1] - (double)pos[3*f+1];
  double ez = (double)pos[3*t+2] - (double)pos[3*f+2];
  double sh[36];
  compute_sh36(ex,ey,ez,sh);
  double d = sqrt(ex*ex+ey*ey+ez*ez);

  // soft one-hot radial embedding
  double emb[20];
  const double step = 3.0/21.0;
  const double cemb = 1.14136 * exp(2.0);
  for (int jb=0;jb<20;jb++){
    double v = step*(double)(jb+1);
    double diff = (d - v)/step;
    double a = diff + 1.0, b = 1.0 - diff;
    double sa = (a > 0.0) ? exp(-1.0/a) : 0.0;
    double sb = (b > 0.0) ? exp(-1.0/b) : 0.0;
    emb[jb] = cemb * sa * sb;
  }
  // MLP: h = silu(emb@W1/sqrt(20))*1.679 ; tw = h@W2/sqrt(50)
  double tw[5] = {0,0,0,0,0};
  const double is20 = 0.22360679774997896964;
  const double is50 = 0.14142135623730950488;
  for (int kk=0;kk<50;kk++){
    double z = 0.0;
    for (int jb=0;jb<20;jb++) z += emb[jb]*(double)w1[jb*50+kk];
    z *= is20;
    double hk = (z / (1.0 + exp(-z))) * 1.679;
    for (int i=0;i<5;i++) tw[i] += hk * (double)w2[kk*5+i];
  }
  for (int i=0;i<5;i++) tw[i] *= is50;

  double xs = (double)x[t];
  // tp1: per l, alpha*(w)*(x)*(sh_l @ W3J1_l)
  const int w1off[5] = {0,1,10,35,84};
  int fo = 0;
  for (int l=0;l<5;l++){
    int nl = 2*l+1;
    double scale = sqrt((double)nl) * tw[l] * xs;
    for (int kq=0;kq<nl;kq++){
      double acc = 0.0;
      for (int jq=0;jq<nl;jq++) acc += sh[l*l+jq]*w3j1[w1off[l]+jq*nl+kq];
      atomicAdd(&node_acc[slot*25 + fo + kq], scale*acc);
    }
    fo += nl;
  }
}

// K6: tp2 on Co-edges + reduce to the 5-component output
__global__ void out_kernel(const int2* __restrict__ ei, const int* __restrict__ flag,
                           const float* __restrict__ pos, const double* __restrict__ node_acc,
                           const double* __restrict__ w3j2, const float* __restrict__ tp2w,
                           const int* __restrict__ co_count, const int* __restrict__ co_edges,
                           float* __restrict__ out){
  __shared__ double red[64*5];
  double acc[5] = {0,0,0,0,0};
  int n = *co_count; if (n > CAP) n = CAP;
  const double inv_sqrt6 = 0.40824829046386301637;   // 1/sqrt(NUM_NEIGHBORS)
  const double alpha2    = 0.67419986246324704794;   // sqrt(5/11)
  const int pl1[11]  = {0,1,1,2,2,2,3,3,3,4,4};
  const int pl2[11]  = {2,1,3,0,2,4,1,3,5,2,4};
  const int poff[11] = {0,25,70,175,200,325,550,655,900,1285,1510};

  for (int idx = threadIdx.x; idx < n; idx += blockDim.x){
    int e = co_edges[idx];
    int2 fe = ei[e];
    int f = fe.x, t = fe.y;
    int slot = flag[t] - 1;
    if (slot < 0 || slot >= CAP) continue;
    double ex = (double)pos[3*t+0] - (double)pos[3*f+0];
    double ey = (double)pos[3*t+1] - (double)pos[3*f+1];
    double ez = (double)pos[3*t+2] - (double)pos[3*f+2];
    double sh[36];
    compute_sh36(ex,ey,ez,sh);
    double nodev[25];
    for (int j=0;j<25;j++) nodev[j] = node_acc[slot*25+j]*inv_sqrt6;
    for (int p=0;p<11;p++){
      int l1 = pl1[p], l2 = pl2[p], n1 = 2*l1+1, n2 = 2*l2+1;
      const double* W = w3j2 + poff[p];
      double wp = alpha2*(double)tp2w[p];
      for (int i=0;i<n1;i++){
        double fi = nodev[l1*l1+i];
        for (int j=0;j<n2;j++){
          double fs = wp*fi*sh[l2*l2+j];
          const double* Wij = W + (i*n2+j)*5;
          for (int k=0;k<5;k++) acc[k] += fs*Wij[k];
        }
      }
    }
  }
  for (int k=0;k<5;k++) red[threadIdx.x*5+k] = acc[k];
  __syncthreads();
  if (threadIdx.x < 5){
    double s = 0.0;
    for (int t2=0;t2<64;t2++) s += red[t2*5+threadIdx.x];
    out[threadIdx.x] = (float)s;
  }
}

// ---------------- launcher ----------------

extern "C" void kernel_launch(void* const* d_in, const int* in_sizes, int n_in,
                              void* d_out, int out_size, void* d_ws, size_t ws_size,
                              hipStream_t stream){
  const float* x    = (const float*)d_in[0];
  const float* pos  = (const float*)d_in[1];
  const int*   ei   = (const int*)d_in[2];
  const float* w1   = (const float*)d_in[3];
  const float* w2   = (const float*)d_in[4];
  const float* tp2w = (const float*)d_in[5];
  int N = in_sizes[0];
  int E = in_sizes[2] / 2;

  char* ws = (char*)d_ws;
  size_t o = 0;
  int* counts = (int*)(ws + o); o += (size_t)N*4;
  int* flag   = (int*)(ws + o); o += (size_t)N*4;
  o = (o + 7) & ~(size_t)7;
  unsigned long long* key = (unsigned long long*)(ws + o); o += 8;
  int* co_count = (int*)(ws + o); o += 4;
  int* s_count  = (int*)(ws + o); o += 4;
  int* m_count  = (int*)(ws + o); o += 8;            // 4 bytes + pad
  int* co_edges = (int*)(ws + o); o += (size_t)CAP*4;
  int* m_edges  = (int*)(ws + o); o += (size_t)MCAP*4;
  o = (o + 7) & ~(size_t)7;
  double* node_acc = (double*)(ws + o); o += (size_t)CAP*25*8;
  double* w3j1 = (double*)(ws + o); o += 165*8;
  double* w3j2 = (double*)(ws + o); o += 1915*8;
  size_t zero_bytes = o;   // includes Wigner tables: setup kernel accumulates

  hipMemsetAsync(d_ws, 0, zero_bytes, stream);

  // 2080 entries x 8 term-slots
  w3j_setup_kernel<<<(2080*8 + 255)/256, 256, 0, stream>>>(w3j1, w3j2);

  const int2* ei2 = (const int2*)ei;
  int eblocks = (E + 255)/256;
  int nblocks = (N + 255)/256;
  count_kernel  <<<eblocks, 256, 0, stream>>>(ei2, counts, E);
  argmax_kernel <<<nblocks, 256, 0, stream>>>(counts, key, N);
  find_co_kernel<<<eblocks, 256, 0, stream>>>(ei2, key, flag, co_count, s_count, co_edges, N, E);
  collect_kernel<<<eblocks, 256, 0, stream>>>(ei2, flag, m_count, m_edges, E);
  feat_kernel   <<<(MCAP+255)/256, 256, 0, stream>>>(ei2, flag, pos, x, w1, w2, w3j1,
                                                     m_count, m_edges, node_acc);
  out_kernel    <<<1, 64, 0, stream>>>(ei2, flag, pos, node_acc, w3j2, tp2w,
                                       co_count, co_edges, (float*)d_out);
}

// Round 3
// 208.937 us; speedup vs baseline: 1.9989x; 1.3421x over previous
//
#include <hip/hip_runtime.h>
#include <math.h>

#define CAP   2048    // max edges out of Co / max |S|
#define MCAP  32768   // max edges whose from-node is in S

// ---------------- double-precision helpers (setup only) ----------------

__device__ double cg_coef_lut(int j1,int m1,int j2,int m2,int j3,int m3, const double* __restrict__ fact){
  if (m1 + m2 != m3) return 0.0;
  double pref = sqrt((2.0*j3+1.0) * fact[j1+j2-j3] * fact[j1-j2+j3] * fact[-j1+j2+j3]
                     / fact[j1+j2+j3+1]);
  pref *= sqrt(fact[j1+m1]*fact[j1-m1]*fact[j2+m2]*fact[j2-m2]*fact[j3+m3]*fact[j3-m3]);
  double s = 0.0;
  for (int k = 0; k <= j1+j2-j3; ++k){
    int d2 = j1-m1-k, d3 = j2+m2-k, d4 = j3-j2+m1+k, d5 = j3-j1-m2+k;
    if (d2 < 0 || d3 < 0 || d4 < 0 || d5 < 0) continue;
    double den = fact[k]*fact[j1+j2-j3-k]*fact[d2]*fact[d3]*fact[d4]*fact[d5];
    s += ((k & 1) ? -1.0 : 1.0) / den;
  }
  return pref * s;
}

__device__ double wigner_c_val_lut(int j1,int j2,int j3,int m1,int m2,int m3, const double* __restrict__ fact){
  if (m1+m2+m3 != 0) return 0.0;
  int e = j1 - j2 - m3;
  double sign = (e & 1) ? -1.0 : 1.0;
  return sign / sqrt(2.0*j3+1.0) * cg_coef_lut(j1,m1,j2,m2,j3,-m3,fact);
}

__device__ int conjU_row(int l, int i, int* cols, double* re, double* im){
  int mr = i - l;
  const double irt2 = 0.70710678118654752440;
  if (mr == 0){ cols[0]=l; re[0]=1.0; im[0]=0.0; return 1; }
  int m = mr > 0 ? mr : -mr;
  double sgn = (m & 1) ? -1.0 : 1.0;
  if (mr > 0){
    cols[0]=l+m; re[0]=sgn*irt2; im[0]=0.0;
    cols[1]=l-m; re[1]=irt2;     im[1]=0.0;
  } else {
    cols[0]=l+m; re[0]=0.0; im[0]= sgn*irt2;
    cols[1]=l-m; re[1]=0.0; im[1]=-irt2;
  }
  return 2;
}

// ---------------- float SH: polynomial, no transcendentals -----------------
// cos(m*phi)/sin(m*phi) via Chebyshev recurrence from (x,y); Legendre via the
// same recurrences as the reference; normalization via small integer products.
__device__ void compute_sh36f(float ex, float ey, float ez, float* __restrict__ sh){
  float r = sqrtf(ex*ex + ey*ey + ez*ez);
  float x = ex/r, y = ey/r, z = ez/r;
  float t = 1.0f - z*z;
  t = t < 0.0f ? 0.0f : (t > 1.0f ? 1.0f : t);
  float s = sqrtf(t);
  float rxy = sqrtf(x*x + y*y);
  float c1, s1;
  if (rxy > 1e-30f){ c1 = x/rxy; s1 = y/rxy; } else { c1 = 1.0f; s1 = 0.0f; }  // atan2(0,0)=0
  float cm[6], sm[6];
  cm[0] = 1.0f; sm[0] = 0.0f;
  for (int m = 1; m <= 5; ++m){
    cm[m] = cm[m-1]*c1 - sm[m-1]*s1;
    sm[m] = sm[m-1]*c1 + cm[m-1]*s1;
  }
  float P[6][6];
  P[0][0] = 1.0f;
  for (int m=1;m<=5;m++) P[m][m] = (float)(2*m-1)*s*P[m-1][m-1];
  for (int m=0;m<5;m++)  P[m+1][m] = (float)(2*m+1)*z*P[m][m];
  for (int l=2;l<=5;l++)
    for (int m=0;m<=l-2;m++)
      P[l][m] = ((float)(2*l-1)*z*P[l-1][m] - (float)(l-1+m)*P[l-2][m])/(float)(l-m);
  const float rt2 = 1.41421356237309504880f;
  for (int l=0;l<=5;l++){
    for (int m=-l;m<=l;m++){
      int am = m < 0 ? -m : m;
      float ratio = 1.0f;                       // (l+am)!/(l-am)!
      for (int k = l-am+1; k <= l+am; ++k) ratio *= (float)k;
      float c = sqrtf((float)(2*l+1)/ratio);
      if (m != 0) c *= rt2;
      float ang = (m < 0) ? sm[am] : ((m > 0) ? cm[am] : 1.0f);
      sh[l*l + m + l] = c * P[l][am] * ang;
    }
  }
}

// ---------------- kernels ----------------

// K1: Wigner tables (float), one thread per (entry, term); tables pre-zeroed.
__global__ void w3j_setup_kernel(float* __restrict__ w3j1, float* __restrict__ w3j2){
  __shared__ double sfact[16];
  if (threadIdx.x == 0){
    double r = 1.0;
    sfact[0] = 1.0;
    for (int i = 1; i < 16; ++i){ r *= (double)i; sfact[i] = r; }
  }
  __syncthreads();

  int gid = blockIdx.x*blockDim.x + threadIdx.x;
  int entry = gid >> 3;
  int combo = gid & 7;
  if (entry >= 165 + 1915) return;

  int j1, j2, j3, ii, jj, kk;
  float* dst;
  if (entry < 165){
    const int l1off[5] = {0,1,10,35,84};
    int l = 4;
    for (int q = 1; q < 5; ++q) if (entry < l1off[q]){ l = q-1; break; }
    int t = entry - l1off[l];
    int n = 2*l+1;
    j1 = 0; j2 = l; j3 = l;
    ii = 0; jj = t / n; kk = t % n;
    dst = &w3j1[entry];
  } else {
    int t2 = entry - 165;
    const int pl1[11]  = {0,1,1,2,2,2,3,3,3,4,4};
    const int pl2[11]  = {2,1,3,0,2,4,1,3,5,2,4};
    const int poff[11] = {0,25,70,175,200,325,550,655,900,1285,1510};
    int p = 10;
    for (int q = 1; q < 11; ++q) if (t2 < poff[q]){ p = q-1; break; }
    int t = t2 - poff[p];
    j1 = pl1[p]; j2 = pl2[p]; j3 = 2;
    int n2 = 2*j2+1;
    ii = t / (n2*5); int rem = t % (n2*5); jj = rem / 5; kk = rem % 5;
    dst = &w3j2[t2];
  }

  int c1[2], c2[2], c3[2];
  double r1[2], i1[2], r2[2], i2[2], r3[2], i3[2];
  int n1 = conjU_row(j1, ii, c1, r1, i1);
  int n2 = conjU_row(j2, jj, c2, r2, i2);
  int n3 = conjU_row(j3, kk, c3, r3, i3);
  int a = (combo >> 2) & 1, b = (combo >> 1) & 1, c = combo & 1;
  if (a >= n1 || b >= n2 || c >= n3) return;

  int m1 = c1[a]-j1, m2 = c2[b]-j2, m3 = c3[c]-j3;
  if (m1 + m2 + m3 != 0) return;
  double wc = wigner_c_val_lut(j1,j2,j3,m1,m2,m3,sfact);
  if (wc == 0.0) return;
  double pr = r1[a]*r2[b] - i1[a]*i2[b];
  double pi = r1[a]*i2[b] + i1[a]*r2[b];
  double qr = pr*r3[c] - pi*i3[c];
  atomicAdd(dst, (float)(wc*qr));
}

// K2: bincount(edge_to)
__global__ void count_kernel(const int2* __restrict__ ei, int* __restrict__ counts, int E){
  int e = blockIdx.x*blockDim.x + threadIdx.x;
  if (e < E) atomicAdd(&counts[ei[e].y], 1);
}

// K3: argmax with first-index tie-break via packed key
__global__ void argmax_kernel(const int* __restrict__ counts, unsigned long long* __restrict__ key, int N){
  __shared__ unsigned long long sred[256];
  int i = blockIdx.x*blockDim.x + threadIdx.x;
  unsigned long long k = 0;
  if (i < N){
    unsigned long long c = (unsigned long long)(unsigned int)counts[i];
    k = (c << 32) | (unsigned int)(N-1-i);
  }
  sred[threadIdx.x] = k;
  __syncthreads();
  for (int s = 128; s > 0; s >>= 1){
    if (threadIdx.x < s){
      unsigned long long o = sred[threadIdx.x+s];
      if (o > sred[threadIdx.x]) sred[threadIdx.x] = o;
    }
    __syncthreads();
  }
  if (threadIdx.x == 0) atomicMax(key, sred[0]);
}

// K4: collect edges with edge_from==Co; flag their targets (set S)
__global__ void find_co_kernel(const int2* __restrict__ ei, const unsigned long long* __restrict__ key,
                               int* __restrict__ flag, int* __restrict__ co_count,
                               int* __restrict__ s_count, int* __restrict__ co_edges, int N, int E){
  int e = blockIdx.x*blockDim.x + threadIdx.x;
  if (e >= E) return;
  int Co = N - 1 - (int)(unsigned int)(*key & 0xffffffffull);
  int2 fe = ei[e];
  if (fe.x != Co) return;
  int p = atomicAdd(co_count, 1);
  if (p < CAP) co_edges[p] = e;
  int v = fe.y;
  if (atomicCAS(&flag[v], 0, -1) == 0){
    int slot = atomicAdd(s_count, 1);
    flag[v] = (slot < CAP) ? (slot + 1) : 0;
  }
}

// K5a: collect edges with edge_from in S
__global__ void collect_kernel(const int2* __restrict__ ei, const int* __restrict__ flag,
                               int* __restrict__ m_count, int* __restrict__ m_edges, int E){
  int e = blockIdx.x*blockDim.x + threadIdx.x;
  if (e >= E) return;
  if (flag[ei[e].x] > 0){
    int p = atomicAdd(m_count, 1);
    if (p < MCAP) m_edges[p] = e;
  }
}

// K5b: per-edge pipeline (emb -> MLP -> tp1), float math, HW transcendentals
__global__ void feat_kernel(const int2* __restrict__ ei, const int* __restrict__ flag,
                            const float* __restrict__ pos, const float* __restrict__ x,
                            const float* __restrict__ w1, const float* __restrict__ w2,
                            const float* __restrict__ w3j1,
                            const int* __restrict__ m_count, const int* __restrict__ m_edges,
                            float* __restrict__ node_acc){
  int idx = blockIdx.x*blockDim.x + threadIdx.x;
  int n = *m_count; if (n > MCAP) n = MCAP;
  if (idx >= n) return;
  int e = m_edges[idx];
  int2 fe = ei[e];
  int f = fe.x, t = fe.y;
  int slot = flag[f] - 1;
  if (slot < 0 || slot >= CAP) return;

  float ex = pos[3*t+0] - pos[3*f+0];
  float ey = pos[3*t+1] - pos[3*f+1];
  float ez = pos[3*t+2] - pos[3*f+2];
  float sh[36];
  compute_sh36f(ex,ey,ez,sh);
  float d = sqrtf(ex*ex+ey*ey+ez*ez);

  // soft one-hot radial embedding
  float emb[20];
  const float step = 3.0f/21.0f;
  const float cemb = 1.14136f * 7.38905609893065f;   // 1.14136*e^2
  for (int jb=0;jb<20;jb++){
    float v = step*(float)(jb+1);
    float diff = (d - v)/step;
    float a = diff + 1.0f, b = 1.0f - diff;
    float sa = (a > 0.0f) ? __expf(-1.0f/a) : 0.0f;
    float sb = (b > 0.0f) ? __expf(-1.0f/b) : 0.0f;
    emb[jb] = cemb * sa * sb;
  }
  // MLP: h = silu(emb@W1/sqrt(20))*1.679 ; tw = h@W2/sqrt(50)
  float tw[5] = {0,0,0,0,0};
  const float is20 = 0.22360679774997896964f;
  const float is50 = 0.14142135623730950488f;
  for (int kk=0;kk<50;kk++){
    float z = 0.0f;
    for (int jb=0;jb<20;jb++) z += emb[jb]*w1[jb*50+kk];
    z *= is20;
    float hk = (z / (1.0f + __expf(-z))) * 1.679f;
    for (int i=0;i<5;i++) tw[i] += hk * w2[kk*5+i];
  }
  for (int i=0;i<5;i++) tw[i] *= is50;

  float xs = x[t];
  const int w1off[5] = {0,1,10,35,84};
  const float alphal[5] = {1.0f, 1.73205080756887729353f, 2.23606797749978969641f,
                           2.64575131106459059050f, 3.0f};
  int fo = 0;
  for (int l=0;l<5;l++){
    int nl = 2*l+1;
    float scale = alphal[l] * tw[l] * xs;
    for (int kq=0;kq<nl;kq++){
      float acc = 0.0f;
      for (int jq=0;jq<nl;jq++) acc += sh[l*l+jq]*w3j1[w1off[l]+jq*nl+kq];
      atomicAdd(&node_acc[slot*25 + fo + kq], scale*acc);
    }
    fo += nl;
  }
}

// K6: tp2 on Co-edges + reduce to the 5-component output
__global__ void out_kernel(const int2* __restrict__ ei, const int* __restrict__ flag,
                           const float* __restrict__ pos, const float* __restrict__ node_acc,
                           const float* __restrict__ w3j2, const float* __restrict__ tp2w,
                           const int* __restrict__ co_count, const int* __restrict__ co_edges,
                           float* __restrict__ out){
  __shared__ float red[64*5];
  float acc[5] = {0,0,0,0,0};
  int n = *co_count; if (n > CAP) n = CAP;
  const float inv_sqrt6 = 0.40824829046386301637f;   // 1/sqrt(6)
  const float alpha2    = 0.67419986246324704794f;   // sqrt(5/11)
  const int pl1[11]  = {0,1,1,2,2,2,3,3,3,4,4};
  const int pl2[11]  = {2,1,3,0,2,4,1,3,5,2,4};
  const int poff[11] = {0,25,70,175,200,325,550,655,900,1285,1510};

  for (int idx = threadIdx.x; idx < n; idx += blockDim.x){
    int e = co_edges[idx];
    int2 fe = ei[e];
    int f = fe.x, t = fe.y;
    int slot = flag[t] - 1;
    if (slot < 0 || slot >= CAP) continue;
    float ex = pos[3*t+0] - pos[3*f+0];
    float ey = pos[3*t+1] - pos[3*f+1];
    float ez = pos[3*t+2] - pos[3*f+2];
    float sh[36];
    compute_sh36f(ex,ey,ez,sh);
    float nodev[25];
    for (int j=0;j<25;j++) nodev[j] = node_acc[slot*25+j]*inv_sqrt6;
    for (int p=0;p<11;p++){
      int l1 = pl1[p], l2 = pl2[p], n1 = 2*l1+1, n2 = 2*l2+1;
      const float* W = w3j2 + poff[p];
      float wp = alpha2*tp2w[p];
      for (int i=0;i<n1;i++){
        float fi = nodev[l1*l1+i];
        for (int j=0;j<n2;j++){
          float fs = wp*fi*sh[l2*l2+j];
          const float* Wij = W + (i*n2+j)*5;
          for (int k=0;k<5;k++) acc[k] += fs*Wij[k];
        }
      }
    }
  }
  for (int k=0;k<5;k++) red[threadIdx.x*5+k] = acc[k];
  __syncthreads();
  if (threadIdx.x < 5){
    float s = 0.0f;
    for (int t2=0;t2<64;t2++) s += red[t2*5+threadIdx.x];
    out[threadIdx.x] = s;
  }
}

// ---------------- launcher ----------------

extern "C" void kernel_launch(void* const* d_in, const int* in_sizes, int n_in,
                              void* d_out, int out_size, void* d_ws, size_t ws_size,
                              hipStream_t stream){
  const float* x    = (const float*)d_in[0];
  const float* pos  = (const float*)d_in[1];
  const int*   ei   = (const int*)d_in[2];
  const float* w1   = (const float*)d_in[3];
  const float* w2   = (const float*)d_in[4];
  const float* tp2w = (const float*)d_in[5];
  int N = in_sizes[0];
  int E = in_sizes[2] / 2;

  char* ws = (char*)d_ws;
  size_t o = 0;
  int* counts = (int*)(ws + o); o += (size_t)N*4;
  int* flag   = (int*)(ws + o); o += (size_t)N*4;
  o = (o + 7) & ~(size_t)7;
  unsigned long long* key = (unsigned long long*)(ws + o); o += 8;
  int* co_count = (int*)(ws + o); o += 4;
  int* s_count  = (int*)(ws + o); o += 4;
  int* m_count  = (int*)(ws + o); o += 8;
  int* co_edges = (int*)(ws + o); o += (size_t)CAP*4;
  int* m_edges  = (int*)(ws + o); o += (size_t)MCAP*4;
  float* node_acc = (float*)(ws + o); o += (size_t)CAP*25*4;
  float* w3j1 = (float*)(ws + o); o += 165*4;
  float* w3j2 = (float*)(ws + o); o += 1915*4;
  size_t zero_bytes = o;   // includes Wigner tables: setup kernel accumulates

  hipMemsetAsync(d_ws, 0, zero_bytes, stream);

  w3j_setup_kernel<<<(2080*8 + 255)/256, 256, 0, stream>>>(w3j1, w3j2);

  const int2* ei2 = (const int2*)ei;
  int eblocks = (E + 255)/256;
  int nblocks = (N + 255)/256;
  count_kernel  <<<eblocks, 256, 0, stream>>>(ei2, counts, E);
  argmax_kernel <<<nblocks, 256, 0, stream>>>(counts, key, N);
  find_co_kernel<<<eblocks, 256, 0, stream>>>(ei2, key, flag, co_count, s_count, co_edges, N, E);
  collect_kernel<<<eblocks, 256, 0, stream>>>(ei2, flag, m_count, m_edges, E);
  feat_kernel   <<<(MCAP+255)/256, 256, 0, stream>>>(ei2, flag, pos, x, w1, w2, w3j1,
                                                     m_count, m_edges, node_acc);
  out_kernel    <<<1, 64, 0, stream>>>(ei2, flag, pos, node_acc, w3j2, tp2w,
                                       co_count, co_edges, (float*)d_out);
}